// Round 7
// baseline (231.105 us; speedup 1.0000x reference)
//
#include <hip/hip_runtime.h>

// Problem constants: b=1, m=128, n=256 (positions), c=22 classes
#define NC    22
#define NROW  (NC*NC)        // 484 floats per (i,j) coupling block
#define NJ    256
#define NI    256
#define NM    128
#define JG    8              // j's per superstep
#define NQJ   4              // j-quarters (blockIdx.y) -> 1024 blocks, 4/CU
#define JQ    (NJ/NQJ)       // 64 j's per block
#define SS    (JQ/JG)        // 8 supersteps
#define ROWDW 16             // dwords per (j,c) row: 32 bf16 (d padded 22->32)
#define JROW  (NC*ROWDW)     // 352 dwords per j
#define TILEDW (JG*JROW)     // 2816 dwords per buffer (11264 B)
#define F4PS  (JG*NROW/4)    // 968 float4 staged per superstep
#define REP   2              // DIAGNOSTIC: double the kernel to surface its
                             // rocprof row above the ~73us poison fills.
                             // acc accumulates both reps; store *0.5 (exact
                             // same math to ~1ulp; absmax tol 0.25).

typedef __attribute__((ext_vector_type(8))) short short8;  // bf16x8 A/B frag
typedef __attribute__((ext_vector_type(4))) float f32x4;   // fp32x4 C/D frag

__device__ inline uint32_t bf16rne(float x) {              // fp32 -> bf16 bits
    uint32_t u = __float_as_uint(x);
    u += 0x7FFFu + ((u >> 16) & 1u);
    return u >> 16;
}

// part[jq][i][m][c] = sum_{j in quarter} eij[i,j,c,v[m,j]] * mask_vec[v[m,j]]
// MFMA formulation: hi = A(one-hot over (j,d)) x B(em), K-block = 32 (one j).
// B-frag (lane n=c, quad q holds B[k=q*8+t][n]) reads 8 consecutive d's ==
// native eij order -> ds_read_b128, no transpose. A-frag built in VALU from
// an LDS-staged v-table. EXACT R0 BASELINE (201.2us) + REP diagnostic loop.
__global__ __launch_bounds__(256) void potts_mfma(
    const int*   __restrict__ variant,   // [128,256] int32
    const float* __restrict__ eij,       // [256,256,22,22]
    const float* __restrict__ mask_vec,  // [22]
    float*       __restrict__ part)      // [4,256,128,22] workspace
{
    const int i    = blockIdx.x;
    const int jq   = blockIdx.y;
    const int tid  = threadIdx.x;
    const int lane = tid & 63;
    const int wv   = tid >> 6;           // wave 0..3
    const int q    = lane >> 4;          // k-quad / row-quad
    const int nl   = lane & 15;          // fragment row/col index

    __shared__ uint32_t tile[2][TILEDW]; // bf16 em tiles, 22528 B
    __shared__ int      vtab[2][JG][NM]; // v[m][j] per superstep, 8192 B
    // total 30720 B -> 4 blocks/CU (123 KB), 16 waves/CU

    // Zero the d-pad (w=11..15 of every (j,c) row) once per buffer; staging
    // never writes there, MFMA reads it as B[k=22..31][*]. A has zeros at
    // d>=22 but junk here could be NaN (NaN*0=NaN) -> must be 0.
    for (int p = tid; p < 2 * JG * NC * 5; p += 256) {
        const int b  = p / (JG * NC * 5), r = p % (JG * NC * 5);
        const int jl = r / (NC * 5),     r2 = r % (NC * 5);
        tile[b][jl * JROW + (r2 / 5) * ROWDW + 11 + r2 % 5] = 0;
    }

    // Staging decomposition: float4 f4 = r*256+tid covers 968 float4 = 8 j of
    // 484 floats. 484/4=121 float4/j (no j straddle); each float4 = two
    // float2s, each within one 22-float c-row (22 even). Mask folded here.
    int   l0[4], l1[4];
    float mk[4][4];
    bool  act[4];
    #pragma unroll
    for (int r = 0; r < 4; ++r) {
        const int f4 = r * 256 + tid;
        act[r] = (f4 < F4PS);
        const int fc = act[r] ? f4 : 0;
        const int jl = fc / 121, r4 = fc % 121;
        const int f2a = 2 * r4, f2b = f2a + 1;
        const int ca = f2a / 11, wa = f2a % 11;
        const int cb = f2b / 11, wb = f2b % 11;
        l0[r] = jl * JROW + ca * ROWDW + wa;
        l1[r] = jl * JROW + cb * ROWDW + wb;
        mk[r][0] = mask_vec[2 * wa];  mk[r][1] = mask_vec[2 * wa + 1];
        mk[r][2] = mask_vec[2 * wb];  mk[r][3] = mask_vec[2 * wb + 1];
    }

    const float4* gsrc = (const float4*)eij + (size_t)(i * NJ + jq * JQ) * 121;

    // Wave-constant fragment addresses. nt=1 covers c=16..31; c>=22 lanes are
    // clamped to row 0 (real data, never NaN); their D columns are discarded.
    const int c1   = 16 + nl;
    const int off0 = nl * ROWDW + q * 4;
    const int off1 = (c1 < NC ? c1 : 0) * ROWDW + q * 4;
    const int m0a  = wv * 16;            // m-tiles: wv and wv+4
    const int m0b  = wv * 16 + 64;

    f32x4 acc_a0 = {0.f,0.f,0.f,0.f}, acc_a1 = {0.f,0.f,0.f,0.f};
    f32x4 acc_b0 = {0.f,0.f,0.f,0.f}, acc_b1 = {0.f,0.f,0.f,0.f};

    for (int rep = 0; rep < REP; ++rep) {
        // Prefetch superstep 0 (em float4s + variant dwords).
        // Rep-boundary hazard: stage(buf 0) at rep1-s0 occurs after ALL waves
        // passed barrier(s7), which proves rep0-s6's reads of buf 0 retired --
        // identical invariant to the steady-state loop.
        float4 pf[4];
        int    vr[4];
        #pragma unroll
        for (int r = 0; r < 4; ++r)
            if (act[r]) pf[r] = gsrc[r * 256 + tid];
        #pragma unroll
        for (int r = 0; r < 4; ++r) {
            const int t = r * 256 + tid; // t<1024: m=t>>3, jj=t&7 (32B chunks)
            vr[r] = variant[(t >> 3) * NJ + jq * JQ + (t & 7)];
        }

        for (int s = 0; s < SS; ++s) {
            const int bsel = s & 1;
            uint32_t* buf = tile[bsel];

            // Stage em tile as bf16 (mask folded) + v-table
            #pragma unroll
            for (int r = 0; r < 4; ++r) {
                if (act[r]) {
                    const float4 v = pf[r];
                    buf[l0[r]] = bf16rne(v.x * mk[r][0])
                               | (bf16rne(v.y * mk[r][1]) << 16);
                    buf[l1[r]] = bf16rne(v.z * mk[r][2])
                               | (bf16rne(v.w * mk[r][3]) << 16);
                }
            }
            #pragma unroll
            for (int r = 0; r < 4; ++r) {
                const int t = r * 256 + tid;
                vtab[bsel][t & 7][t >> 3] = vr[r];
            }
            __syncthreads();
            // One barrier per superstep: writes to buffer b at superstep s+1
            // occur only after this barrier, which requires all reads of b
            // from superstep s-1 to have retired (program order). Proven R1.

            // Prefetch next superstep
            if (s + 1 < SS) {
                const float4* gn = gsrc + (size_t)(s + 1) * F4PS;
                #pragma unroll
                for (int r = 0; r < 4; ++r)
                    if (act[r]) pf[r] = gn[r * 256 + tid];
                #pragma unroll
                for (int r = 0; r < 4; ++r) {
                    const int t = r * 256 + tid;
                    vr[r] = variant[(t >> 3) * NJ + jq * JQ + (s + 1) * JG + (t & 7)];
                }
            }

            // 8 j's: per wave per j: 2 vtab b32 (broadcast) + 2 B-frag b128
            // (conflict-free: 64 lanes hit 64 distinct 16B chunks) + 4 MFMA
            #pragma unroll
            for (int jl = 0; jl < JG; ++jl) {
                const uint32_t* jrow = buf + jl * JROW;
                const short8 bf0 = *(const short8*)(jrow + off0);
                const short8 bf1 = *(const short8*)(jrow + off1);

                const int va = vtab[bsel][jl][m0a + nl];
                const int vb = vtab[bsel][jl][m0b + nl];

                // A-frag: one-hot at d=v within k-quad q. Element t of this
                // lane is A[m][q*8+t]; pair-packed: dword u holds d=q*8+2u,
                // +2u+1. pat = 1.0bf16 in (v&1) half; placed iff v>>1==q*4+u.
                const uint32_t pa = 0x3F80u << ((va & 1) << 4);
                const uint32_t pb = 0x3F80u << ((vb & 1) << 4);
                const int ha = va >> 1, hb = vb >> 1, kb = q * 4;
                union { uint32_t u[4]; short8 s; } fa, fb;
                #pragma unroll
                for (int t = 0; t < 4; ++t) {
                    fa.u[t] = (ha == kb + t) ? pa : 0u;
                    fb.u[t] = (hb == kb + t) ? pb : 0u;
                }

                acc_a0 = __builtin_amdgcn_mfma_f32_16x16x32_bf16(fa.s, bf0, acc_a0, 0, 0, 0);
                acc_a1 = __builtin_amdgcn_mfma_f32_16x16x32_bf16(fa.s, bf1, acc_a1, 0, 0, 0);
                acc_b0 = __builtin_amdgcn_mfma_f32_16x16x32_bf16(fb.s, bf0, acc_b0, 0, 0, 0);
                acc_b1 = __builtin_amdgcn_mfma_f32_16x16x32_bf16(fb.s, bf1, acc_b1, 0, 0, 0);
            }
        }
    }

    // Epilogue: C/D layout col=lane&15, row=(lane>>4)*4+reg (m89-verified).
    // *0.5f undoes the REP=2 double-accumulation (exact to ~1 ulp).
    const float sc = 1.0f / (float)REP;
    float* pbase = part + ((size_t)jq * NI + i) * NM * NC;
    #pragma unroll
    for (int t = 0; t < 4; ++t) {
        const int ra = m0a + q * 4 + t, rb = m0b + q * 4 + t;
        pbase[ra * NC + nl] = acc_a0[t] * sc;
        pbase[rb * NC + nl] = acc_b0[t] * sc;
        if (c1 < NC) {
            pbase[ra * NC + c1] = acc_a1[t] * sc;
            pbase[rb * NC + c1] = acc_b1[t] * sc;
        }
    }
}

// motifs[m,i,c] = ei[i,c] + sum_jq part[jq,i,m,c];  logits[m,i]=motifs[m,i,v[m,i]]
__global__ __launch_bounds__(256) void potts_reduce(
    const float* __restrict__ part,      // [4,256,128,22]
    const int*   __restrict__ variant,   // [128,256]
    const float* __restrict__ ei,        // [256,22]
    float*       __restrict__ out_motifs,// [128,256,22]
    float*       __restrict__ out_logits)// [128,256]
{
    const int i    = blockIdx.x;
    const int tid  = threadIdx.x;
    const int m    = tid & 127;
    const int half = tid >> 7;
    const int cc0  = half * 11;

    const float* p0 = part + (((size_t)0 * NI + i) * NM + m) * NC + cc0;
    const float* p1 = part + (((size_t)1 * NI + i) * NM + m) * NC + cc0;
    const float* p2 = part + (((size_t)2 * NI + i) * NM + m) * NC + cc0;
    const float* p3 = part + (((size_t)3 * NI + i) * NM + m) * NC + cc0;
    const float* eirow = ei + i * NC;
    float* mout = out_motifs + ((size_t)m * NI + i) * NC;
    const int vi = variant[m * NJ + i];

    float logit = 0.f;
    #pragma unroll
    for (int k = 0; k < 11; ++k) {
        const float v = p0[k] + p1[k] + p2[k] + p3[k] + eirow[cc0 + k];
        mout[cc0 + k] = v;
        if (cc0 + k == vi) logit = v;
    }
    if (vi >= cc0 && vi < cc0 + 11)
        out_logits[m * NI + i] = logit;
}

// variant_logit[m] = sigma * sum_i (logits[m,i]-logits[0,i]) * vm[m,i]*vm[0,i]
__global__ __launch_bounds__(64) void potts_pool(
    const float* __restrict__ logits,  // [128,256]
    const float* __restrict__ vmask,   // [128,256]
    const float* __restrict__ sigma,   // [1]
    float*       __restrict__ out_vl)  // [128]
{
    const int m    = blockIdx.x;
    const int lane = threadIdx.x;
    float s = 0.f;
    #pragma unroll
    for (int qq = 0; qq < 4; ++qq) {
        const int i = lane + 64 * qq;
        const float vl = logits[m * NI + i] - logits[i];
        s += vl * vmask[m * NI + i] * vmask[i];
    }
    #pragma unroll
    for (int off = 32; off > 0; off >>= 1)
        s += __shfl_down(s, off, 64);
    if (lane == 0) out_vl[m] = sigma[0] * s;
}

extern "C" void kernel_launch(void* const* d_in, const int* in_sizes, int n_in,
                              void* d_out, int out_size, void* d_ws, size_t ws_size,
                              hipStream_t stream) {
    const int*   variant  = (const int*)  d_in[0];  // [1,128,256] int32
    const float* vmask    = (const float*)d_in[1];  // [1,128,256]
    const float* eij      = (const float*)d_in[2];  // [1,256,256,22,22]
    const float* ei       = (const float*)d_in[3];  // [1,256,22]
    const float* mask_vec = (const float*)d_in[4];  // [22]
    const float* sigma    = (const float*)d_in[5];  // [1]

    float* out        = (float*)d_out;
    float* out_motifs = out;                        // 128*256*22
    float* out_logits = out_motifs + NM * NI * NC;  // 128*256
    float* out_vl     = out_logits + NM * NI;       // 128

    float* part = (float*)d_ws;                     // 4*256*128*22 fl = 11.5 MB

    dim3 gridA(NI, NQJ);
    potts_mfma<<<gridA, 256, 0, stream>>>(variant, eij, mask_vec, part);
    potts_reduce<<<NI, 256, 0, stream>>>(part, variant, ei,
                                         out_motifs, out_logits);
    potts_pool<<<NM, 64, 0, stream>>>(out_logits, vmask, sigma, out_vl);
}

// Round 8
// 226.230 us; speedup vs baseline: 1.0215x; 1.0215x over previous
//
#include <hip/hip_runtime.h>

// Problem constants: b=1, m=128, n=256 (positions), c=22 classes
#define NC    22
#define NROW  (NC*NC)        // 484 floats per (i,j) coupling block
#define NJ    256
#define NI    256
#define NM    128
#define NQJ   4              // j-quarters (blockIdx.y) -> 1024 blocks, 4/CU
#define JQ    (NJ/NQJ)       // 64 j's per block (16 per wave)
#define JPW   16             // j's per wave
#define SLOTF 496            // floats per staged j: 484 data + 12 zero pad
#define NSL   4              // per-wave slot ring (depth-2 prefetch)
#define SLAB  (NI*NM*NC)     // 720896 floats per j-quarter partial slab

typedef __attribute__((ext_vector_type(8))) short short8;  // bf16x8 A/B frag
typedef __attribute__((ext_vector_type(4))) float f32x4;   // fp32x4 C/D frag

__device__ __forceinline__ uint32_t bf16rne(float x) {     // fp32 -> bf16 bits
    uint32_t u = __float_as_uint(x);
    u += 0x7FFFu + ((u >> 16) & 1u);
    return u >> 16;
}

__device__ __forceinline__ uint32_t pk_bf16(float lo, float hi) { // 2xf32->bf16x2
    uint32_t r;
    asm("v_cvt_pk_bf16_f32 %0, %1, %2" : "=v"(r) : "v"(lo), "v"(hi));
    return r;
}

// Async global->LDS, 16 B/lane. Global addr is PER-LANE; LDS dest is
// wave-uniform base + lane*16 (m104/m173 semantics).
__device__ __forceinline__ void gload_lds16(const void* g, void* l) {
    __builtin_amdgcn_global_load_lds(
        (const __attribute__((address_space(1))) void*)g,
        (__attribute__((address_space(3))) void*)l, 16, 0, 0);
}

#define WAITV(n) asm volatile("s_waitcnt vmcnt(" #n ")" ::: "memory")

union u32x4s8 { uint32_t u[4]; short8 s; };

// part[jq][i][m][c] = sum_{j in quarter} eij[i,j,c,v[m,j]] * mask_vec[v[m,j]]
//
// R7 diagnosis: 43us/pass, L3-hot pass same speed => NOT memory-bound;
// VALUBusy 39% == the fp32->bf16 staging VALU (every eij float through
// bf16rne), LDS conflicts == vtab 8-way staging writes. Fix: stage RAW f32
// via global_load_lds (zero staging VALU / zero staging LDS-write conflicts),
// convert at B-frag read (ds_read_b64 x4 + cvt_pk x4; conversion count per
// float stays 1 because each wave owns its j's exclusively: wave-private
// no-barrier main loop from R6 + 4 blocks/CU overlap from R0 + counted-vmcnt
// depth-2 ring from T4, per-wave counting exact: 2 DMA ops per j).
__global__ __launch_bounds__(256, 4) void potts_mfma(
    const int*   __restrict__ variant,   // [128,256] int32
    const float* __restrict__ eij,       // [256,256,22,22]
    const float* __restrict__ mask_vec,  // [22]
    float*       __restrict__ part)      // [4,256,128,22] workspace (11.5 MB)
{
    const int i    = blockIdx.x;
    const int jq   = blockIdx.y;
    const int tid  = threadIdx.x;
    const int lane = tid & 63;
    const int w    = tid >> 6;           // wave 0..3 (owns j-locals w*16..+15)
    const int q    = lane >> 4;          // k-quad / row-quad
    const int nl   = lane & 15;          // fragment row/col index
    const int kb   = q * 4;

    __shared__ float         slots[4][NSL][SLOTF]; // raw f32 eij, 31744 B
    __shared__ unsigned char vtp[JQ * NM];         // [j][nl][t] packed v, 8192 B
    __shared__ uint32_t      patTab[32];           // bf16(mask[v])<<((v&1)*16)
    // total 40064 B -> 4 blocks/CU (<=160.3 KB incl. granularity), 16 waves/CU

    // ---- one-time init (no VMEM in flight yet) ----
    if (tid < 32) {
        const uint32_t mb = (tid < NC) ? bf16rne(mask_vec[tid]) : 0u;
        patTab[tid] = mb << ((tid & 1) << 4);
    }
    // Slot pads (floats 484..495): B-frag c=21,q=3 reads floats 486..493 as
    // B[k=22..31]; A is 0 there but junk could be NaN (NaN*0=NaN) -> zero.
    if (tid < 4 * NSL * (SLOTF - 484)) {
        const int ww = tid / (NSL * 12), r = tid % (NSL * 12);
        slots[ww][r / 12][484 + r % 12] = 0.f;
    }
    // vtp layout [j-local][nl][t]: one ds_read_b64 per (wave,j) yields all 8
    // m-tile class ids for this lane. m = t*16+nl = p&127 exactly.
    for (int p = tid; p < JQ * NM; p += 256) {
        const int jl = p >> 7, mm = p & 127;
        vtp[jl * 128 + (mm & 15) * 8 + (mm >> 4)] =
            (unsigned char)variant[mm * NJ + jq * JQ + jl];
    }
    __syncthreads();   // commits vtp/patTab/pads

    // Per-wave global source base (per-lane addresses; j chunks: floats
    // 0..255 and 228..483, 28-float overlap written twice with identical
    // data -> benign; proven R1/R2).
    const float* gbase = eij + (size_t)(i * NJ + jq * JQ + w * JPW) * NROW;

    // Wave-constant fragment float-offsets within a slot. nt c-tile 1 covers
    // c=16..31; c>=22 lanes clamp to row 0 (real data, never NaN; D dropped).
    const int c1   = 16 + nl;
    const int c1r  = (c1 < NC) ? c1 : 0;
    const int fo0  = nl * NC + q * 8;    // byte 8-aligned -> ds_read_b64 x4
    const int fo1  = c1r * NC + q * 8;

    f32x4 acc[8][2];
    #pragma unroll
    for (int t = 0; t < 8; ++t) {
        acc[t][0] = (f32x4){0.f, 0.f, 0.f, 0.f};
        acc[t][1] = (f32x4){0.f, 0.f, 0.f, 0.f};
    }

    // Prologue: fill ring slots 0,1 (4 DMA ops outstanding).
    #pragma unroll
    for (int J = 0; J < 2; ++J) {
        const float* g = gbase + (size_t)J * NROW;
        float* l = &slots[w][J][0];
        gload_lds16(g + lane * 4, l);
        gload_lds16(g + 228 + lane * 4, l + 228);
    }

    #pragma unroll
    for (int j = 0; j < JPW; ++j) {
        // Issue j+2 early (latency hides under compute of j, j+1).
        if (j + 2 < JPW) {
            const float* g = gbase + (size_t)(j + 2) * NROW;
            float* l = &slots[w][(j + 2) & (NSL - 1)][0];
            gload_lds16(g + lane * 4, l);
            gload_lds16(g + 228 + lane * 4, l + 228);
        }
        // Own-wave counted wait: after it, slot j's 2 DMAs have landed.
        // Outstanding then: j<=13 -> L(j+1),L(j+2)=4; j==14 -> L(15)=2; j==15 -> 0.
        if (j < 14)      WAITV(4);
        else if (j < 15) WAITV(2);
        else             WAITV(0);

        const float* jb = &slots[w][j & (NSL - 1)][0];

        // B-frags: 8x ds_read_b64 (2-way bank aliasing max = free) + 8 cvt_pk.
        const float2* r0 = (const float2*)jb + (fo0 >> 1);
        const float2* r1 = (const float2*)jb + (fo1 >> 1);
        const float2 x0 = r0[0], x1 = r0[1], x2 = r0[2], x3 = r0[3];
        const float2 y0 = r1[0], y1 = r1[1], y2 = r1[2], y3 = r1[3];
        u32x4s8 B0, B1;
        B0.u[0] = pk_bf16(x0.x, x0.y);  B0.u[1] = pk_bf16(x1.x, x1.y);
        B0.u[2] = pk_bf16(x2.x, x2.y);  B0.u[3] = pk_bf16(x3.x, x3.y);
        B1.u[0] = pk_bf16(y0.x, y0.y);  B1.u[1] = pk_bf16(y1.x, y1.y);
        B1.u[2] = pk_bf16(y2.x, y2.y);  B1.u[3] = pk_bf16(y3.x, y3.y);

        // All 8 m-tile class ids in one b64 (16 distinct chunks, q-broadcast).
        const uint32_t* vj = (const uint32_t*)&vtp[(w * JPW + j) * 128 + nl * 8];
        const uint32_t vlo = vj[0], vhi = vj[1];

        #pragma unroll
        for (int t = 0; t < 8; ++t) {
            const uint32_t vd = (t < 4) ? vlo : vhi;
            const int      va = (vd >> ((t & 3) * 8)) & 0xFF;
            const uint32_t pa = patTab[va];       // bf16(mask[va]), pre-shifted
            const int      ha = va >> 1;
            u32x4s8 A;
            #pragma unroll
            for (int tt = 0; tt < 4; ++tt)
                A.u[tt] = (ha == kb + tt) ? pa : 0u;
            acc[t][0] = __builtin_amdgcn_mfma_f32_16x16x32_bf16(A.s, B0.s, acc[t][0], 0, 0, 0);
            acc[t][1] = __builtin_amdgcn_mfma_f32_16x16x32_bf16(A.s, B1.s, acc[t][1], 0, 0, 0);
        }
    }

    // ---- cross-wave j-reduction in LDS (3 barriers), then part store ----
    __syncthreads();                     // all waves done (own vmcnt drained)
    float* red   = &slots[0][0][0];      // 2 slabs x 128x22 f32 = 22528 B
    float* myred = red + (w & 1) * (NM * NC);
    // C/D layout (m89-verified): col = lane&15, row = (lane>>4)*4 + reg.
    if (w < 2) {
        #pragma unroll
        for (int t = 0; t < 8; ++t)
            #pragma unroll
            for (int tt = 0; tt < 4; ++tt) {
                const int m = t * 16 + kb + tt;
                myred[m * NC + nl] = acc[t][0][tt];
                if (c1 < NC) myred[m * NC + c1] = acc[t][1][tt];
            }
    }
    __syncthreads();
    if (w >= 2) {                        // disjoint-element RMW, race-free
        #pragma unroll
        for (int t = 0; t < 8; ++t)
            #pragma unroll
            for (int tt = 0; tt < 4; ++tt) {
                const int m = t * 16 + kb + tt;
                myred[m * NC + nl] += acc[t][0][tt];
                if (c1 < NC) myred[m * NC + c1] += acc[t][1][tt];
            }
    }
    __syncthreads();
    float* pbase = part + ((size_t)jq * NI + i) * (NM * NC);
    #pragma unroll
    for (int k = 0; k < 11; ++k) {       // 11*256 = 2816 = NM*NC exactly
        const int p = k * 256 + tid;
        pbase[p] = red[p] + red[NM * NC + p];
    }
}

// motifs[m,i,c] = ei[i,c] + sum_jq part[jq,i,m,c];  logits[m,i]=motifs[m,i,v[m,i]]
__global__ __launch_bounds__(256) void potts_reduce(
    const float* __restrict__ part,      // [4,256,128,22]
    const int*   __restrict__ variant,   // [128,256]
    const float* __restrict__ ei,        // [256,22]
    float*       __restrict__ out_motifs,// [128,256,22]
    float*       __restrict__ out_logits)// [128,256]
{
    const int i    = blockIdx.x;
    const int tid  = threadIdx.x;
    const int m    = tid & 127;
    const int half = tid >> 7;
    const int cc0  = half * 11;

    const float* p0 = part + (((size_t)0 * NI + i) * NM + m) * NC + cc0;
    const float* p1 = part + (((size_t)1 * NI + i) * NM + m) * NC + cc0;
    const float* p2 = part + (((size_t)2 * NI + i) * NM + m) * NC + cc0;
    const float* p3 = part + (((size_t)3 * NI + i) * NM + m) * NC + cc0;
    const float* eirow = ei + i * NC;
    float* mout = out_motifs + ((size_t)m * NI + i) * NC;
    const int vi = variant[m * NJ + i];

    float logit = 0.f;
    #pragma unroll
    for (int k = 0; k < 11; ++k) {
        const float v = p0[k] + p1[k] + p2[k] + p3[k] + eirow[cc0 + k];
        mout[cc0 + k] = v;
        if (cc0 + k == vi) logit = v;
    }
    if (vi >= cc0 && vi < cc0 + 11)
        out_logits[m * NI + i] = logit;
}

// variant_logit[m] = sigma * sum_i (logits[m,i]-logits[0,i]) * vm[m,i]*vm[0,i]
__global__ __launch_bounds__(64) void potts_pool(
    const float* __restrict__ logits,  // [128,256]
    const float* __restrict__ vmask,   // [128,256]
    const float* __restrict__ sigma,   // [1]
    float*       __restrict__ out_vl)  // [128]
{
    const int m    = blockIdx.x;
    const int lane = threadIdx.x;
    float s = 0.f;
    #pragma unroll
    for (int qq = 0; qq < 4; ++qq) {
        const int i = lane + 64 * qq;
        const float vl = logits[m * NI + i] - logits[i];
        s += vl * vmask[m * NI + i] * vmask[i];
    }
    #pragma unroll
    for (int off = 32; off > 0; off >>= 1)
        s += __shfl_down(s, off, 64);
    if (lane == 0) out_vl[m] = sigma[0] * s;
}

extern "C" void kernel_launch(void* const* d_in, const int* in_sizes, int n_in,
                              void* d_out, int out_size, void* d_ws, size_t ws_size,
                              hipStream_t stream) {
    const int*   variant  = (const int*)  d_in[0];  // [1,128,256] int32
    const float* vmask    = (const float*)d_in[1];  // [1,128,256]
    const float* eij      = (const float*)d_in[2];  // [1,256,256,22,22]
    const float* ei       = (const float*)d_in[3];  // [1,256,22]
    const float* mask_vec = (const float*)d_in[4];  // [22]
    const float* sigma    = (const float*)d_in[5];  // [1]

    float* out        = (float*)d_out;
    float* out_motifs = out;                        // 128*256*22
    float* out_logits = out_motifs + NM * NI * NC;  // 128*256
    float* out_vl     = out_logits + NM * NI;       // 128

    float* part = (float*)d_ws;                     // 4*256*128*22 fl = 11.5 MB

    dim3 gridA(NI, NQJ);
    potts_mfma<<<gridA, 256, 0, stream>>>(variant, eij, mask_vec, part);
    potts_reduce<<<NI, 256, 0, stream>>>(part, variant, ei,
                                         out_motifs, out_logits);
    potts_pool<<<NM, 64, 0, stream>>>(out_logits, vmask, sigma, out_vl);
}